// Round 1
// baseline (294.134 us; speedup 1.0000x reference)
//
#include <hip/hip_runtime.h>
#include <hip/hip_bf16.h>

typedef __attribute__((ext_vector_type(8))) short short8;   // 8 bf16 = 4 VGPRs
typedef __attribute__((ext_vector_type(4))) float float4v;  // 4 fp32

#define LDSROW 136  // shorts per Wt row: 128 + 8 pad -> 272 B = 17*16 B (bank-group spread)

static __device__ inline short f2bf(float f) {
    union { float f; unsigned u; } v; v.f = f;
    unsigned u = v.u;
    u += 0x7fffu + ((u >> 16) & 1u);   // round-to-nearest-even
    return (short)(u >> 16);
}

// out[b, n'] = sum_k' A[b, k'] * W[k', n']
//   A row (contiguous in eq_freq): k'<64 -> xr[k'] (pilot->1), k'>=64 -> xi[k'-64] (pilot->0)
//   n'<64 -> out_real[n'], n'>=64 -> out_imag[n'-64]
//   W[k'][n'] = [[cos, sin], [-sin, cos]] (cos/sin are symmetric 64x64, scaled 1/64)
__global__ __launch_bounds__(256, 4)
void ofdm_idft_kernel(const float* __restrict__ eq,
                      const float* __restrict__ cosk,
                      const float* __restrict__ sink,
                      float* __restrict__ out)
{
    __shared__ short Wt[128 * LDSROW];  // Wt[n'][k'] = W[k'][n'] in bf16, 34816 B

    const int tid = threadIdx.x;

    // ---- Build Wt (wave-uniform branches: each wave covers one half-row of k) ----
    for (int idx = tid; idx < 128 * 128; idx += 256) {
        const int n = idx >> 7;      // 0..127 (output col)
        const int k = idx & 127;     // 0..127 (input k)
        const int nn = n & 63, km = k & 63;
        float v;
        if (n < 64) {
            v = (k < 64) ? cosk[n * 64 + k] : -sink[n * 64 + km];
        } else {
            v = (k < 64) ? sink[nn * 64 + k] : cosk[nn * 64 + km];
        }
        Wt[n * LDSROW + k] = f2bf(v);
    }
    __syncthreads();

    const int lane = tid & 63;
    const int wave = tid >> 6;
    const int m    = lane & 15;   // M row within tile / N col within tile / D col
    const int q    = lane >> 4;   // quad: k-offset for A/B frags, row-group for D

    const unsigned long long PMASK =
        (1ull << 11) | (1ull << 25) | (1ull << 39) | (1ull << 53);

    const int wave_id = blockIdx.x * 4 + wave;   // 4096 waves, 64 batches each

    for (int t = 0; t < 4; ++t) {
        const int b0 = wave_id * 64 + t * 16;
        const float* arow = eq + (size_t)(b0 + m) * 128;

        // ---- A fragments: A[m = lane&15][k = kk*32 + q*8 + j], j=0..7 ----
        short8 afrag[4];
        #pragma unroll
        for (int kk = 0; kk < 4; ++kk) {
            const int kbase = kk * 32 + q * 8;
            const float4v x0 = *(const float4v*)(arow + kbase);
            const float4v x1 = *(const float4v*)(arow + kbase + 4);
            short8 f;
            #pragma unroll
            for (int j = 0; j < 8; ++j) {
                float xv = (j < 4) ? x0[j] : x1[j - 4];
                const int k = kbase + j;
                if ((PMASK >> (k & 63)) & 1ull)
                    xv = (k < 64) ? 1.0f : 0.0f;   // pilot: real->1, imag->0
                f[j] = f2bf(xv);
            }
            afrag[kk] = f;
        }

        // ---- MFMA: 8 n-tiles x 4 k-steps ----
        float4v acc[8];
        #pragma unroll
        for (int nt = 0; nt < 8; ++nt) acc[nt] = (float4v){0.f, 0.f, 0.f, 0.f};

        #pragma unroll
        for (int kk = 0; kk < 4; ++kk) {
            #pragma unroll
            for (int nt = 0; nt < 8; ++nt) {
                // B[k = kk*32 + q*8 + j][n = nt*16 + m] -> 8 consecutive k in Wt row n
                const short8 bfrag =
                    *(const short8*)&Wt[(nt * 16 + m) * LDSROW + kk * 32 + q * 8];
                acc[nt] = __builtin_amdgcn_mfma_f32_16x16x32_bf16(
                    afrag[kk], bfrag, acc[nt], 0, 0, 0);
            }
        }

        // ---- Store: D[row = q*4 + r][col = nt*16 + m] ----
        float* orow = out + (size_t)b0 * 128;
        #pragma unroll
        for (int nt = 0; nt < 8; ++nt) {
            #pragma unroll
            for (int r = 0; r < 4; ++r) {
                orow[(size_t)(q * 4 + r) * 128 + nt * 16 + m] = acc[nt][r];
            }
        }
    }
}

extern "C" void kernel_launch(void* const* d_in, const int* in_sizes, int n_in,
                              void* d_out, int out_size, void* d_ws, size_t ws_size,
                              hipStream_t stream) {
    const float* eq   = (const float*)d_in[0];
    const float* cosk = (const float*)d_in[1];
    const float* sink = (const float*)d_in[2];
    float* out = (float*)d_out;
    // 1024 blocks * 4 waves * 64 batches = 262144 batches, exact cover
    hipLaunchKernelGGL(ofdm_idft_kernel, dim3(1024), dim3(256), 0, stream,
                       eq, cosk, sink, out);
}